// Round 4
// baseline (648.271 us; speedup 1.0000x reference)
//
#include <hip/hip_runtime.h>
#include <hip/hip_bf16.h>
#include <math.h>

// ---------------------------------------------------------------------------
// VaryMambaModel: batch=1, L=128
//   PRE_D=2048, D=4096, N=64, K=4, DI1=4096, DI2=8192, DTR1=128, DTR2=256
// Round 3: LDS-free MFMA GEMM (pre-split bf16 activations, in-reg W split),
//          chunked-reduce scan, gate split out.
// ---------------------------------------------------------------------------

typedef __attribute__((ext_vector_type(8))) short short8_t;   // 8 bf16
typedef __attribute__((ext_vector_type(4))) float f32x4;

__device__ __forceinline__ float sigmoidf_(float x) {
  return 1.0f / (1.0f + __expf(-x));
}
__device__ __forceinline__ float softplusf_(float x) {
  return fmaxf(x, 0.0f) + log1pf(expf(-fabsf(x)));
}
__device__ __forceinline__ void splitbf(float f, ushort& h, ushort& lo) {
  __hip_bfloat16 hb = __float2bfloat16(f);
  h = *reinterpret_cast<ushort*>(&hb);
  float hf = __bfloat162float(hb);
  __hip_bfloat16 lb = __float2bfloat16(f - hf);
  lo = *reinterpret_cast<ushort*>(&lb);
}

// ---------------- prep: x0 = pe + cond*to_cond_w + to_cond_b -> split -------
__global__ __launch_bounds__(256) void k_prep(const float* __restrict__ pe,
                                              const float* __restrict__ cw,
                                              const float* __restrict__ cb,
                                              const float* __restrict__ cond,
                                              ushort* __restrict__ xh,
                                              ushort* __restrict__ xl) {
  int i = blockIdx.x * 256 + threadIdx.x;  // 128*2048
  int d = i & 2047;
  float v = pe[i] + cond[0] * cw[d] + cb[d];
  splitbf(v, xh[i], xl[i]);
}

// ---------------- MFMA GEMM: P[s] = X[128xK] * W[NxK]^T ---------------------
// LDS-free. Tile 128m x 128n, 4 waves (wave w: n in [32w,32w+32)).
// A (activation) pre-split bf16 hi/lo in global, loaded as fragments.
// W f32 loaded in fragment order, split to bf16 hi/lo in registers.
#define KSTEP 32
__global__ __launch_bounds__(256, 3) void k_gemm(const ushort* __restrict__ Xh,
                                                 const ushort* __restrict__ Xl,
                                                 int ldx,
                                                 const float* __restrict__ W, int ldw,
                                                 float* __restrict__ P,
                                                 int N, int Ks) {
  const int n0   = blockIdx.x * 128;
  const int s    = blockIdx.z;
  const int kbeg = s * Ks;
  const int t    = threadIdx.x;
  const int l    = t & 63;
  const int w    = t >> 6;
  const int lr   = l & 15;
  const int lg   = l >> 4;

  f32x4 acc[8][2];
#pragma unroll
  for (int mi = 0; mi < 8; ++mi)
#pragma unroll
    for (int ni = 0; ni < 2; ++ni) acc[mi][ni] = (f32x4)(0.0f);

  // A fragment pointers: row 16*mi+lr, k window start kbeg + 8*lg
  const ushort* pAh[8];
  const ushort* pAl[8];
#pragma unroll
  for (int mi = 0; mi < 8; ++mi) {
    const size_t off = (size_t)(16 * mi + lr) * ldx + kbeg + 8 * lg;
    pAh[mi] = Xh + off;
    pAl[mi] = Xl + off;
  }
  // W fragment pointers: rows n0+32w+16ni+lr
  const float* pW0 = W + (size_t)(n0 + 32 * w + lr) * ldw + kbeg + 8 * lg;
  const float* pW1 = pW0 + (size_t)16 * ldw;

  for (int kk = 0; kk < Ks; kk += KSTEP) {
    const float4 w0a = *(const float4*)(pW0);
    const float4 w0b = *(const float4*)(pW0 + 4);
    const float4 w1a = *(const float4*)(pW1);
    const float4 w1b = *(const float4*)(pW1 + 4);
    pW0 += KSTEP; pW1 += KSTEP;

    short8_t bh0, bl0, bh1, bl1;
    {
      const float f0[8] = {w0a.x, w0a.y, w0a.z, w0a.w, w0b.x, w0b.y, w0b.z, w0b.w};
      const float f1[8] = {w1a.x, w1a.y, w1a.z, w1a.w, w1b.x, w1b.y, w1b.z, w1b.w};
#pragma unroll
      for (int e = 0; e < 8; ++e) {
        ushort h, lo;
        splitbf(f0[e], h, lo);
        bh0[e] = (short)h; bl0[e] = (short)lo;
        splitbf(f1[e], h, lo);
        bh1[e] = (short)h; bl1[e] = (short)lo;
      }
    }
#pragma unroll
    for (int mi = 0; mi < 8; ++mi) {
      const short8_t ah = *(const short8_t*)pAh[mi];
      const short8_t al = *(const short8_t*)pAl[mi];
      pAh[mi] += KSTEP; pAl[mi] += KSTEP;
      acc[mi][0] = __builtin_amdgcn_mfma_f32_16x16x32_bf16(ah, bh0, acc[mi][0], 0, 0, 0);
      acc[mi][1] = __builtin_amdgcn_mfma_f32_16x16x32_bf16(ah, bh1, acc[mi][1], 0, 0, 0);
      acc[mi][0] = __builtin_amdgcn_mfma_f32_16x16x32_bf16(ah, bl0, acc[mi][0], 0, 0, 0);
      acc[mi][1] = __builtin_amdgcn_mfma_f32_16x16x32_bf16(ah, bl1, acc[mi][1], 0, 0, 0);
      acc[mi][0] = __builtin_amdgcn_mfma_f32_16x16x32_bf16(al, bh0, acc[mi][0], 0, 0, 0);
      acc[mi][1] = __builtin_amdgcn_mfma_f32_16x16x32_bf16(al, bh1, acc[mi][1], 0, 0, 0);
    }
  }

  // epilogue: C/D layout col=lane&15, row=4*(lane>>4)+j
  float* Pd = P + (size_t)s * 128 * N + n0;
#pragma unroll
  for (int mi = 0; mi < 8; ++mi)
#pragma unroll
    for (int ni = 0; ni < 2; ++ni) {
#pragma unroll
      for (int j = 0; j < 4; ++j) {
        const int m = 16 * mi + 4 * lg + j;
        Pd[(size_t)m * N + 32 * w + 16 * ni + lr] = acc[mi][ni][j];
      }
    }
}

// ---------------- reduce partials + epilogues -------------------------------
// ep bit0: softplus+bias ; bit1: write bf16 split ; bit2: write f32
__global__ __launch_bounds__(256) void k_reduce(const float* __restrict__ P,
                                                float* __restrict__ Y,
                                                ushort* __restrict__ Yh,
                                                ushort* __restrict__ Yl,
                                                int MN, int N, int S, int ep,
                                                const float* __restrict__ bias) {
  int i = (blockIdx.x * 256 + threadIdx.x) * 4;
  if (i >= MN) return;
  float4 v = *(const float4*)&P[i];
  for (int s = 1; s < S; ++s) {
    float4 p = *(const float4*)&P[(size_t)s * MN + i];
    v.x += p.x; v.y += p.y; v.z += p.z; v.w += p.w;
  }
  if (ep & 1) {
    int n = i % N;
    const float4 b = *(const float4*)&bias[n];
    v.x = softplusf_(v.x + b.x);
    v.y = softplusf_(v.y + b.y);
    v.z = softplusf_(v.z + b.z);
    v.w = softplusf_(v.w + b.w);
  }
  if (ep & 4) *(float4*)&Y[i] = v;
  if (ep & 2) {
    ushort4 h4, l4;
    splitbf(v.x, h4.x, l4.x);
    splitbf(v.y, h4.y, l4.y);
    splitbf(v.z, h4.z, l4.z);
    splitbf(v.w, h4.w, l4.w);
    *(ushort4*)&Yh[i] = h4;
    *(ushort4*)&Yl[i] = l4;
  }
}

// stage-A reduce: sum groups of 8 partials (for S>16)
__global__ __launch_bounds__(256) void k_reduceA(const float* __restrict__ P,
                                                 float* __restrict__ Y, int MN) {
  int g = blockIdx.y;
  int i = (blockIdx.x * 256 + threadIdx.x) * 4;
  if (i >= MN) return;
  const float* Pp = P + (size_t)g * 8 * MN;
  float4 v = *(const float4*)&Pp[i];
  for (int s = 1; s < 8; ++s) {
    float4 p = *(const float4*)&Pp[(size_t)s * MN + i];
    v.x += p.x; v.y += p.y; v.z += p.z; v.w += p.w;
  }
  *(float4*)&Y[(size_t)g * MN + i] = v;
}

// ---------------- depthwise causal conv (K=4) + silu + split ----------------
__global__ __launch_bounds__(256) void k_conv_silu(const float* __restrict__ xz,
                                                   const float* __restrict__ cw,
                                                   const float* __restrict__ cb,
                                                   float* __restrict__ xc,
                                                   ushort* __restrict__ xch,
                                                   ushort* __restrict__ xcl,
                                                   int DI) {
  int i = blockIdx.x * 256 + threadIdx.x;  // over 128*DI
  int l = i / DI;
  int d = i - l * DI;
  const float4 w = *(const float4*)&cw[d * 4];
  const float* xr = xz + d;
  int ld = 2 * DI;
  float s = cb[d];
  s += w.w * xr[l * ld];
  if (l >= 1) s += w.z * xr[(l - 1) * ld];
  if (l >= 2) s += w.y * xr[(l - 2) * ld];
  if (l >= 3) s += w.x * xr[(l - 3) * ld];
  float v = s * sigmoidf_(s);
  xc[i] = v;
  splitbf(v, xch[i], xcl[i]);
}

// ---------------- selective scan v2: chunked LDS reduce ---------------------
__global__ __launch_bounds__(256) void k_scan(const float* __restrict__ dt,
                                              const float* __restrict__ xc,
                                              const float* __restrict__ dbc,
                                              const float* __restrict__ A_log,
                                              const float* __restrict__ Dp,
                                              float* __restrict__ y,
                                              int DI, int DTR) {
  __shared__ float cs[4][32][65];
  const int wid = threadIdx.x >> 6;
  const int n   = threadIdx.x & 63;
  const int d   = blockIdx.x * 4 + wid;
  const int du  = __builtin_amdgcn_readfirstlane(d);
  const float A  = -__expf(A_log[(size_t)du * 64 + n]);
  const float Dd = Dp[du];
  const int ldbc = DTR + 128;
  const float* Bp = dbc + DTR + n;
  const float* Cp = dbc + DTR + 64 + n;
  float h = 0.0f;
  for (int l0 = 0; l0 < 128; l0 += 32) {
#pragma unroll 8
    for (int l = l0; l < l0 + 32; ++l) {
      float dtv = dt[(size_t)l * DI + du];
      float xcv = xc[(size_t)l * DI + du];
      float dA  = __expf(dtv * A);
      float bx  = dtv * xcv;
      h = fmaf(dA, h, bx * Bp[(size_t)l * ldbc]);
      cs[wid][l - l0][n] = h * Cp[(size_t)l * ldbc];
    }
    __syncthreads();
    const int r = n & 31, hf = n >> 5;
    float ssum = 0.0f;
#pragma unroll
    for (int j = 0; j < 32; ++j) ssum += cs[wid][r][hf * 32 + j];
    ssum += __shfl_xor(ssum, 32, 64);
    if (n < 32) {
      int ll = l0 + r;
      float xcv = xc[(size_t)ll * DI + du];
      y[(size_t)ll * DI + du] = ssum + xcv * Dd;
    }
    __syncthreads();
  }
}

// ---------------- gate: y *= silu(z), write bf16 split ----------------------
__global__ __launch_bounds__(256) void k_gate(const float* __restrict__ yb,
                                              const float* __restrict__ xz,
                                              ushort* __restrict__ yh,
                                              ushort* __restrict__ yl,
                                              int DI, int lg2DI) {
  int i = blockIdx.x * 256 + threadIdx.x;  // over 128*DI
  int l = i >> lg2DI;
  int d = i & (DI - 1);
  float z = xz[((size_t)l << (lg2DI + 1)) + DI + d];
  float v = yb[i] * (z * sigmoidf_(z));
  splitbf(v, yh[i], yl[i]);
}

// ---------------------------------------------------------------------------
struct GemmCtx {
  float* part;
  float* part2;
  long long cap;
};

static inline void gemm(const ushort* Xh, const ushort* Xl, int ldx,
                        const float* W, int ldw,
                        float* dstF, ushort* dstH, ushort* dstL,
                        int N, int K, int Sdes, int ep,
                        const float* bias, const GemmCtx& cx, hipStream_t stream) {
  int S = Sdes;
  if (S > K / KSTEP) S = K / KSTEP;
  if (S < 1) S = 1;
  while (S > 1 && (long long)S * 128 * N > cx.cap) S >>= 1;
  const int Ks = K / S;
  const bool direct = (S == 1 && ep == 4);
  dim3 g(N / 128, 1, S);
  k_gemm<<<g, 256, 0, stream>>>(Xh, Xl, ldx, W, ldw, direct ? dstF : cx.part, N, Ks);
  if (direct) return;
  const int MN = 128 * N;
  const int rb = (MN / 4 + 255) / 256;
  if (S <= 16) {
    k_reduce<<<rb, 256, 0, stream>>>(cx.part, dstF, dstH, dstL, MN, N, S, ep, bias);
  } else {
    k_reduceA<<<dim3(rb, S / 8), 256, 0, stream>>>(cx.part, cx.part2, MN);
    k_reduce<<<rb, 256, 0, stream>>>(cx.part2, dstF, dstH, dstL, MN, N, S / 8, ep, bias);
  }
}

extern "C" void kernel_launch(void* const* d_in, const int* in_sizes, int n_in,
                              void* d_out, int out_size, void* d_ws, size_t ws_size,
                              hipStream_t stream) {
  const float* pe        = (const float*)d_in[0];
  const float* to_cond_w = (const float*)d_in[1];
  const float* to_cond_b = (const float*)d_in[2];
  const float* condition = (const float*)d_in[3];
  const int o = (in_sizes[4] == 1) ? 5 : 4;
  const float* m1_in_proj  = (const float*)d_in[o + 0];
  const float* m1_conv_w   = (const float*)d_in[o + 1];
  const float* m1_conv_b   = (const float*)d_in[o + 2];
  const float* m1_x_proj   = (const float*)d_in[o + 3];
  const float* m1_dt_w     = (const float*)d_in[o + 4];
  const float* m1_dt_b     = (const float*)d_in[o + 5];
  const float* m1_A_log    = (const float*)d_in[o + 6];
  const float* m1_D        = (const float*)d_in[o + 7];
  const float* m1_out_proj = (const float*)d_in[o + 8];
  const float* m2_in_proj  = (const float*)d_in[o + 9];
  const float* m2_conv_w   = (const float*)d_in[o + 10];
  const float* m2_conv_b   = (const float*)d_in[o + 11];
  const float* m2_x_proj   = (const float*)d_in[o + 12];
  const float* m2_dt_w     = (const float*)d_in[o + 13];
  const float* m2_dt_b     = (const float*)d_in[o + 14];
  const float* m2_A_log    = (const float*)d_in[o + 15];
  const float* m2_D        = (const float*)d_in[o + 16];
  const float* m2_out_proj = (const float*)d_in[o + 17];

  float* ws = (float*)d_ws;
  // f32 buffers
  float*  xz   = ws;                 // 2,097,152
  float*  xc   = ws + 2097152;       // 1,048,576
  float*  dbc  = ws + 3145728;       //    49,152
  float*  dtb  = ws + 3194880;       // 1,048,576
  float*  yb   = ws + 4243456;       // 1,048,576
  // bf16 split buffers (ushort), sizes in float-units (=elems/2)
  ushort* x0h  = (ushort*)(ws + 5292032);   // 128*2048 -> 131072 f
  ushort* x0l  = (ushort*)(ws + 5423104);   // 131072 f
  ushort* xch  = (ushort*)(ws + 5554176);   // 128*8192 -> 524288 f
  ushort* xcl  = (ushort*)(ws + 6078464);   // 524288 f
  ushort* dbch = (ushort*)(ws + 6602752);   // 24576 f
  ushort* dbcl = (ushort*)(ws + 6627328);   // 24576 f
  ushort* ybh  = (ushort*)(ws + 6651904);   // 524288 f
  ushort* ybl  = (ushort*)(ws + 7176192);   // 524288 f
  ushort* midh = (ushort*)(ws + 7700480);   // 131072 f
  ushort* midl = (ushort*)(ws + 7831552);   // 131072 f
  float*  part2 = ws + 7962624;      // 524,288
  float*  part  = ws + 8486912;      // rest

  GemmCtx cx;
  cx.part = part;
  cx.part2 = part2;
  cx.cap = (long long)(ws_size / 4) - 8486912;
  if (cx.cap < 0) cx.cap = 0;

  k_prep<<<1024, 256, 0, stream>>>(pe, to_cond_w, to_cond_b, condition, x0h, x0l);

  // ---------------- mamba block 1: DI=4096, DTR=128 ----------------
  gemm(x0h, x0l, 2048, m1_in_proj, 2048, xz, nullptr, nullptr,
       8192, 2048, 8, 4, nullptr, cx, stream);
  k_conv_silu<<<(128 * 4096) / 256, 256, 0, stream>>>(xz, m1_conv_w, m1_conv_b,
                                                      xc, xch, xcl, 4096);
  gemm(xch, xcl, 4096, m1_x_proj, 4096, dbc, dbch, dbcl,
       256, 4096, 128, 6, nullptr, cx, stream);
  gemm(dbch, dbcl, 256, m1_dt_w, 128, dtb, nullptr, nullptr,
       4096, 128, 4, 5, m1_dt_b, cx, stream);
  k_scan<<<1024, 256, 0, stream>>>(dtb, xc, dbc, m1_A_log, m1_D, yb, 4096, 128);
  k_gate<<<(128 * 4096) / 256, 256, 0, stream>>>(yb, xz, ybh, ybl, 4096, 12);
  gemm(ybh, ybl, 4096, m1_out_proj, 4096, nullptr, midh, midl,
       2048, 4096, 16, 2, nullptr, cx, stream);

  // ---------------- mamba block 2: DI=8192, DTR=256 ----------------
  gemm(midh, midl, 2048, m2_in_proj, 2048, xz, nullptr, nullptr,
       16384, 2048, 2, 4, nullptr, cx, stream);
  k_conv_silu<<<(128 * 8192) / 256, 256, 0, stream>>>(xz, m2_conv_w, m2_conv_b,
                                                      xc, xch, xcl, 8192);
  gemm(xch, xcl, 8192, m2_x_proj, 8192, dbc, dbch, dbcl,
       384, 8192, 64, 6, nullptr, cx, stream);
  gemm(dbch, dbcl, 384, m2_dt_w, 256, dtb, nullptr, nullptr,
       8192, 256, 8, 5, m2_dt_b, cx, stream);
  k_scan<<<2048, 256, 0, stream>>>(dtb, xc, dbc, m2_A_log, m2_D, yb, 8192, 256);
  k_gate<<<(128 * 8192) / 256, 256, 0, stream>>>(yb, xz, ybh, ybl, 8192, 13);
  gemm(ybh, ybl, 8192, m2_out_proj, 8192, (float*)d_out, nullptr, nullptr,
       4096, 8192, 8, 4, nullptr, cx, stream);
}

// Round 5
// 358.335 us; speedup vs baseline: 1.8091x; 1.8091x over previous
//
#include <hip/hip_runtime.h>
#include <hip/hip_bf16.h>
#include <math.h>

// ---------------------------------------------------------------------------
// VaryMambaModel: batch=1, L=128
//   PRE_D=2048, D=4096, N=64, K=4, DI1=4096, DI2=8192, DTR1=128, DTR2=256
// Round 4: hybrid MFMA GEMM — A (pre-split bf16 hi/lo) double-buffered in
// LDS (kb-major, conflict-free), W streamed global->reg with 1-iter-ahead
// prefetch + in-reg hi/lo split. Scan v2 + gate from round 3 kept.
// ---------------------------------------------------------------------------

typedef __attribute__((ext_vector_type(8))) short short8_t;   // 8 bf16
typedef __attribute__((ext_vector_type(4))) float f32x4;

__device__ __forceinline__ float sigmoidf_(float x) {
  return 1.0f / (1.0f + __expf(-x));
}
__device__ __forceinline__ float softplusf_(float x) {
  return fmaxf(x, 0.0f) + log1pf(expf(-fabsf(x)));
}
__device__ __forceinline__ void splitbf(float f, ushort& h, ushort& lo) {
  __hip_bfloat16 hb = __float2bfloat16(f);
  h = *reinterpret_cast<ushort*>(&hb);
  float hf = __bfloat162float(hb);
  __hip_bfloat16 lb = __float2bfloat16(f - hf);
  lo = *reinterpret_cast<ushort*>(&lb);
}

// ---------------- prep: x0 = pe + cond*to_cond_w + to_cond_b -> split -------
__global__ __launch_bounds__(256) void k_prep(const float* __restrict__ pe,
                                              const float* __restrict__ cw,
                                              const float* __restrict__ cb,
                                              const float* __restrict__ cond,
                                              ushort* __restrict__ xh,
                                              ushort* __restrict__ xl) {
  int i = blockIdx.x * 256 + threadIdx.x;  // 128*2048
  int d = i & 2047;
  float v = pe[i] + cond[0] * cw[d] + cb[d];
  splitbf(v, xh[i], xl[i]);
}

// ---------------- MFMA GEMM: P[s] = X[128xK] * W[NxK]^T ---------------------
// Tile 128m x 128n, 4 waves (wave w: n-quad 32w). KSTEP=32 f32 k-values.
// A: bf16 hi/lo from global, staged to double-buffered LDS [buf][hl][kb][row][8].
// W: f32 global->reg, prefetched one KSTEP ahead, split to bf16 hi/lo in-reg.
#define KSTEP 32
__global__ __launch_bounds__(256, 2) void k_gemm(const ushort* __restrict__ Xh,
                                                 const ushort* __restrict__ Xl,
                                                 int ldx,
                                                 const float* __restrict__ W, int ldw,
                                                 float* __restrict__ P,
                                                 int N, int Ks) {
  __shared__ ushort As[2][2][4][128][8];   // 32 KB

  const int n0   = blockIdx.x * 128;
  const int s    = blockIdx.z;
  const int kbeg = s * Ks;
  const int t    = threadIdx.x;
  const int l    = t & 63;
  const int w    = t >> 6;
  const int lr   = l & 15;
  const int lg   = l >> 4;

  f32x4 acc[8][2];
#pragma unroll
  for (int mi = 0; mi < 8; ++mi)
#pragma unroll
    for (int ni = 0; ni < 2; ++ni) acc[mi][ni] = (f32x4)(0.0f);

  // A staging: thread handles row srow, kb = skb,skb+1 (32B contiguous global)
  const int srow = t >> 1;
  const int skb  = (t & 1) * 2;
  const ushort* pXh = Xh + (size_t)srow * ldx + kbeg + skb * 8;
  const ushort* pXl = Xl + (size_t)srow * ldx + kbeg + skb * 8;
  // W fragment pointers: rows n0+32w+16ni+lr, k = kbeg + 8*lg
  const float* pW0 = W + (size_t)(n0 + 32 * w + lr) * ldw + kbeg + 8 * lg;
  const float* pW1 = pW0 + (size_t)16 * ldw;

  // ---- prologue: stage chunk 0 into buf 0; load W chunk 0 ----
  {
    short8_t h0 = *(const short8_t*)(pXh);
    short8_t h1 = *(const short8_t*)(pXh + 8);
    short8_t v0 = *(const short8_t*)(pXl);
    short8_t v1 = *(const short8_t*)(pXl + 8);
    *(short8_t*)&As[0][0][skb][srow][0]     = h0;
    *(short8_t*)&As[0][0][skb + 1][srow][0] = h1;
    *(short8_t*)&As[0][1][skb][srow][0]     = v0;
    *(short8_t*)&As[0][1][skb + 1][srow][0] = v1;
  }
  float wcur[16];
  {
    const float4 a = *(const float4*)(pW0);
    const float4 b = *(const float4*)(pW0 + 4);
    const float4 c = *(const float4*)(pW1);
    const float4 d = *(const float4*)(pW1 + 4);
    wcur[0]=a.x; wcur[1]=a.y; wcur[2]=a.z;  wcur[3]=a.w;
    wcur[4]=b.x; wcur[5]=b.y; wcur[6]=b.z;  wcur[7]=b.w;
    wcur[8]=c.x; wcur[9]=c.y; wcur[10]=c.z; wcur[11]=c.w;
    wcur[12]=d.x; wcur[13]=d.y; wcur[14]=d.z; wcur[15]=d.w;
  }
  __syncthreads();

  const int nIter = Ks / KSTEP;
  for (int j = 0; j < nIter; ++j) {
    const int bi = j & 1;
    const bool more = (j + 1 < nIter);
    const int ko = more ? (j + 1) * KSTEP : 0;

    // ---- prefetch next chunk (W regs + A regs), issued before compute ----
    float wnxt[16];
    {
      const float4 a = *(const float4*)(pW0 + ko);
      const float4 b = *(const float4*)(pW0 + ko + 4);
      const float4 c = *(const float4*)(pW1 + ko);
      const float4 d = *(const float4*)(pW1 + ko + 4);
      wnxt[0]=a.x; wnxt[1]=a.y; wnxt[2]=a.z;  wnxt[3]=a.w;
      wnxt[4]=b.x; wnxt[5]=b.y; wnxt[6]=b.z;  wnxt[7]=b.w;
      wnxt[8]=c.x; wnxt[9]=c.y; wnxt[10]=c.z; wnxt[11]=c.w;
      wnxt[12]=d.x; wnxt[13]=d.y; wnxt[14]=d.z; wnxt[15]=d.w;
    }
    short8_t nh0 = *(const short8_t*)(pXh + ko);
    short8_t nh1 = *(const short8_t*)(pXh + ko + 8);
    short8_t nl0 = *(const short8_t*)(pXl + ko);
    short8_t nl1 = *(const short8_t*)(pXl + ko + 8);

    // ---- convert current W to bf16 hi/lo fragments ----
    short8_t bh[2], bl[2];
#pragma unroll
    for (int ni = 0; ni < 2; ++ni)
#pragma unroll
      for (int e = 0; e < 8; ++e) {
        const float f = wcur[ni * 8 + e];
        __hip_bfloat16 hb = __float2bfloat16(f);
        const float hf = __bfloat162float(hb);
        __hip_bfloat16 lb = __float2bfloat16(f - hf);
        bh[ni][e] = (short)*reinterpret_cast<ushort*>(&hb);
        bl[ni][e] = (short)*reinterpret_cast<ushort*>(&lb);
      }

    // ---- MFMA over current LDS buffer ----
#pragma unroll
    for (int mi = 0; mi < 8; ++mi) {
      const short8_t ah = *(const short8_t*)&As[bi][0][lg][16 * mi + lr][0];
      const short8_t al = *(const short8_t*)&As[bi][1][lg][16 * mi + lr][0];
      acc[mi][0] = __builtin_amdgcn_mfma_f32_16x16x32_bf16(ah, bh[0], acc[mi][0], 0, 0, 0);
      acc[mi][1] = __builtin_amdgcn_mfma_f32_16x16x32_bf16(ah, bh[1], acc[mi][1], 0, 0, 0);
      acc[mi][0] = __builtin_amdgcn_mfma_f32_16x16x32_bf16(ah, bl[0], acc[mi][0], 0, 0, 0);
      acc[mi][1] = __builtin_amdgcn_mfma_f32_16x16x32_bf16(ah, bl[1], acc[mi][1], 0, 0, 0);
      acc[mi][0] = __builtin_amdgcn_mfma_f32_16x16x32_bf16(al, bh[0], acc[mi][0], 0, 0, 0);
      acc[mi][1] = __builtin_amdgcn_mfma_f32_16x16x32_bf16(al, bh[1], acc[mi][1], 0, 0, 0);
    }

    // ---- write next A chunk to other buffer; roll W regs ----
    if (more) {
      *(short8_t*)&As[bi ^ 1][0][skb][srow][0]     = nh0;
      *(short8_t*)&As[bi ^ 1][0][skb + 1][srow][0] = nh1;
      *(short8_t*)&As[bi ^ 1][1][skb][srow][0]     = nl0;
      *(short8_t*)&As[bi ^ 1][1][skb + 1][srow][0] = nl1;
#pragma unroll
      for (int e2 = 0; e2 < 16; ++e2) wcur[e2] = wnxt[e2];
    }
    __syncthreads();
  }

  // ---- epilogue: C/D layout col=lane&15, row=4*(lane>>4)+j ----
  float* Pd = P + (size_t)s * 128 * N + n0;
#pragma unroll
  for (int mi = 0; mi < 8; ++mi)
#pragma unroll
    for (int ni = 0; ni < 2; ++ni) {
#pragma unroll
      for (int j = 0; j < 4; ++j) {
        const int m = 16 * mi + 4 * lg + j;
        Pd[(size_t)m * N + 32 * w + 16 * ni + lr] = acc[mi][ni][j];
      }
    }
}

// ---------------- reduce partials + epilogues -------------------------------
// ep bit0: softplus+bias ; bit1: write bf16 split ; bit2: write f32
__global__ __launch_bounds__(256) void k_reduce(const float* __restrict__ P,
                                                float* __restrict__ Y,
                                                ushort* __restrict__ Yh,
                                                ushort* __restrict__ Yl,
                                                int MN, int N, int S, int ep,
                                                const float* __restrict__ bias) {
  int i = (blockIdx.x * 256 + threadIdx.x) * 4;
  if (i >= MN) return;
  float4 v = *(const float4*)&P[i];
  for (int s = 1; s < S; ++s) {
    float4 p = *(const float4*)&P[(size_t)s * MN + i];
    v.x += p.x; v.y += p.y; v.z += p.z; v.w += p.w;
  }
  if (ep & 1) {
    int n = i % N;
    const float4 b = *(const float4*)&bias[n];
    v.x = softplusf_(v.x + b.x);
    v.y = softplusf_(v.y + b.y);
    v.z = softplusf_(v.z + b.z);
    v.w = softplusf_(v.w + b.w);
  }
  if (ep & 4) *(float4*)&Y[i] = v;
  if (ep & 2) {
    ushort4 h4, l4;
    splitbf(v.x, h4.x, l4.x);
    splitbf(v.y, h4.y, l4.y);
    splitbf(v.z, h4.z, l4.z);
    splitbf(v.w, h4.w, l4.w);
    *(ushort4*)&Yh[i] = h4;
    *(ushort4*)&Yl[i] = l4;
  }
}

// stage-A reduce: sum groups of 8 partials (for S>16)
__global__ __launch_bounds__(256) void k_reduceA(const float* __restrict__ P,
                                                 float* __restrict__ Y, int MN) {
  int g = blockIdx.y;
  int i = (blockIdx.x * 256 + threadIdx.x) * 4;
  if (i >= MN) return;
  const float* Pp = P + (size_t)g * 8 * MN;
  float4 v = *(const float4*)&Pp[i];
  for (int s = 1; s < 8; ++s) {
    float4 p = *(const float4*)&Pp[(size_t)s * MN + i];
    v.x += p.x; v.y += p.y; v.z += p.z; v.w += p.w;
  }
  *(float4*)&Y[(size_t)g * MN + i] = v;
}

// ---------------- depthwise causal conv (K=4) + silu + split ----------------
__global__ __launch_bounds__(256) void k_conv_silu(const float* __restrict__ xz,
                                                   const float* __restrict__ cw,
                                                   const float* __restrict__ cb,
                                                   float* __restrict__ xc,
                                                   ushort* __restrict__ xch,
                                                   ushort* __restrict__ xcl,
                                                   int DI) {
  int i = blockIdx.x * 256 + threadIdx.x;  // over 128*DI
  int l = i / DI;
  int d = i - l * DI;
  const float4 w = *(const float4*)&cw[d * 4];
  const float* xr = xz + d;
  int ld = 2 * DI;
  float s = cb[d];
  s += w.w * xr[l * ld];
  if (l >= 1) s += w.z * xr[(l - 1) * ld];
  if (l >= 2) s += w.y * xr[(l - 2) * ld];
  if (l >= 3) s += w.x * xr[(l - 3) * ld];
  float v = s * sigmoidf_(s);
  xc[i] = v;
  splitbf(v, xch[i], xcl[i]);
}

// ---------------- selective scan v2: chunked LDS reduce ---------------------
__global__ __launch_bounds__(256) void k_scan(const float* __restrict__ dt,
                                              const float* __restrict__ xc,
                                              const float* __restrict__ dbc,
                                              const float* __restrict__ A_log,
                                              const float* __restrict__ Dp,
                                              float* __restrict__ y,
                                              int DI, int DTR) {
  __shared__ float cs[4][32][65];
  const int wid = threadIdx.x >> 6;
  const int n   = threadIdx.x & 63;
  const int d   = blockIdx.x * 4 + wid;
  const int du  = __builtin_amdgcn_readfirstlane(d);
  const float A  = -__expf(A_log[(size_t)du * 64 + n]);
  const float Dd = Dp[du];
  const int ldbc = DTR + 128;
  const float* Bp = dbc + DTR + n;
  const float* Cp = dbc + DTR + 64 + n;
  float h = 0.0f;
  for (int l0 = 0; l0 < 128; l0 += 32) {
#pragma unroll 8
    for (int l = l0; l < l0 + 32; ++l) {
      float dtv = dt[(size_t)l * DI + du];
      float xcv = xc[(size_t)l * DI + du];
      float dA  = __expf(dtv * A);
      float bx  = dtv * xcv;
      h = fmaf(dA, h, bx * Bp[(size_t)l * ldbc]);
      cs[wid][l - l0][n] = h * Cp[(size_t)l * ldbc];
    }
    __syncthreads();
    const int r = n & 31, hf = n >> 5;
    float ssum = 0.0f;
#pragma unroll
    for (int j = 0; j < 32; ++j) ssum += cs[wid][r][hf * 32 + j];
    ssum += __shfl_xor(ssum, 32, 64);
    if (n < 32) {
      int ll = l0 + r;
      float xcv = xc[(size_t)ll * DI + du];
      y[(size_t)ll * DI + du] = ssum + xcv * Dd;
    }
    __syncthreads();
  }
}

// ---------------- gate: y *= silu(z), write bf16 split ----------------------
__global__ __launch_bounds__(256) void k_gate(const float* __restrict__ yb,
                                              const float* __restrict__ xz,
                                              ushort* __restrict__ yh,
                                              ushort* __restrict__ yl,
                                              int DI, int lg2DI) {
  int i = blockIdx.x * 256 + threadIdx.x;  // over 128*DI
  int l = i >> lg2DI;
  int d = i & (DI - 1);
  float z = xz[((size_t)l << (lg2DI + 1)) + DI + d];
  float v = yb[i] * (z * sigmoidf_(z));
  splitbf(v, yh[i], yl[i]);
}

// ---------------------------------------------------------------------------
struct GemmCtx {
  float* part;
  float* part2;
  long long cap;
};

static inline void gemm(const ushort* Xh, const ushort* Xl, int ldx,
                        const float* W, int ldw,
                        float* dstF, ushort* dstH, ushort* dstL,
                        int N, int K, int Sdes, int ep,
                        const float* bias, const GemmCtx& cx, hipStream_t stream) {
  int S = Sdes;
  if (S > K / KSTEP) S = K / KSTEP;
  if (S < 1) S = 1;
  while (S > 1 && (long long)S * 128 * N > cx.cap) S >>= 1;
  const int Ks = K / S;
  const bool direct = (S == 1 && ep == 4);
  dim3 g(N / 128, 1, S);
  k_gemm<<<g, 256, 0, stream>>>(Xh, Xl, ldx, W, ldw, direct ? dstF : cx.part, N, Ks);
  if (direct) return;
  const int MN = 128 * N;
  const int rb = (MN / 4 + 255) / 256;
  if (S <= 16) {
    k_reduce<<<rb, 256, 0, stream>>>(cx.part, dstF, dstH, dstL, MN, N, S, ep, bias);
  } else {
    k_reduceA<<<dim3(rb, S / 8), 256, 0, stream>>>(cx.part, cx.part2, MN);
    k_reduce<<<rb, 256, 0, stream>>>(cx.part2, dstF, dstH, dstL, MN, N, S / 8, ep, bias);
  }
}

extern "C" void kernel_launch(void* const* d_in, const int* in_sizes, int n_in,
                              void* d_out, int out_size, void* d_ws, size_t ws_size,
                              hipStream_t stream) {
  const float* pe        = (const float*)d_in[0];
  const float* to_cond_w = (const float*)d_in[1];
  const float* to_cond_b = (const float*)d_in[2];
  const float* condition = (const float*)d_in[3];
  const int o = (in_sizes[4] == 1) ? 5 : 4;
  const float* m1_in_proj  = (const float*)d_in[o + 0];
  const float* m1_conv_w   = (const float*)d_in[o + 1];
  const float* m1_conv_b   = (const float*)d_in[o + 2];
  const float* m1_x_proj   = (const float*)d_in[o + 3];
  const float* m1_dt_w     = (const float*)d_in[o + 4];
  const float* m1_dt_b     = (const float*)d_in[o + 5];
  const float* m1_A_log    = (const float*)d_in[o + 6];
  const float* m1_D        = (const float*)d_in[o + 7];
  const float* m1_out_proj = (const float*)d_in[o + 8];
  const float* m2_in_proj  = (const float*)d_in[o + 9];
  const float* m2_conv_w   = (const float*)d_in[o + 10];
  const float* m2_conv_b   = (const float*)d_in[o + 11];
  const float* m2_x_proj   = (const float*)d_in[o + 12];
  const float* m2_dt_w     = (const float*)d_in[o + 13];
  const float* m2_dt_b     = (const float*)d_in[o + 14];
  const float* m2_A_log    = (const float*)d_in[o + 15];
  const float* m2_D        = (const float*)d_in[o + 16];
  const float* m2_out_proj = (const float*)d_in[o + 17];

  float* ws = (float*)d_ws;
  // f32 buffers
  float*  xz   = ws;                 // 2,097,152
  float*  xc   = ws + 2097152;       // 1,048,576
  float*  dbc  = ws + 3145728;       //    49,152
  float*  dtb  = ws + 3194880;       // 1,048,576
  float*  yb   = ws + 4243456;       // 1,048,576
  // bf16 split buffers (ushort), sizes in float-units (=elems/2)
  ushort* x0h  = (ushort*)(ws + 5292032);   // 131072 f
  ushort* x0l  = (ushort*)(ws + 5423104);   // 131072 f
  ushort* xch  = (ushort*)(ws + 5554176);   // 524288 f
  ushort* xcl  = (ushort*)(ws + 6078464);   // 524288 f
  ushort* dbch = (ushort*)(ws + 6602752);   // 24576 f
  ushort* dbcl = (ushort*)(ws + 6627328);   // 24576 f
  ushort* ybh  = (ushort*)(ws + 6651904);   // 524288 f
  ushort* ybl  = (ushort*)(ws + 7176192);   // 524288 f
  ushort* midh = (ushort*)(ws + 7700480);   // 131072 f
  ushort* midl = (ushort*)(ws + 7831552);   // 131072 f
  float*  part2 = ws + 7962624;      // 524,288
  float*  part  = ws + 8486912;      // rest

  GemmCtx cx;
  cx.part = part;
  cx.part2 = part2;
  cx.cap = (long long)(ws_size / 4) - 8486912;
  if (cx.cap < 0) cx.cap = 0;

  k_prep<<<1024, 256, 0, stream>>>(pe, to_cond_w, to_cond_b, condition, x0h, x0l);

  // ---------------- mamba block 1: DI=4096, DTR=128 ----------------
  gemm(x0h, x0l, 2048, m1_in_proj, 2048, xz, nullptr, nullptr,
       8192, 2048, 8, 4, nullptr, cx, stream);
  k_conv_silu<<<(128 * 4096) / 256, 256, 0, stream>>>(xz, m1_conv_w, m1_conv_b,
                                                      xc, xch, xcl, 4096);
  gemm(xch, xcl, 4096, m1_x_proj, 4096, dbc, dbch, dbcl,
       256, 4096, 128, 6, nullptr, cx, stream);
  gemm(dbch, dbcl, 256, m1_dt_w, 128, dtb, nullptr, nullptr,
       4096, 128, 4, 5, m1_dt_b, cx, stream);
  k_scan<<<1024, 256, 0, stream>>>(dtb, xc, dbc, m1_A_log, m1_D, yb, 4096, 128);
  k_gate<<<(128 * 4096) / 256, 256, 0, stream>>>(yb, xz, ybh, ybl, 4096, 12);
  gemm(ybh, ybl, 4096, m1_out_proj, 4096, nullptr, midh, midl,
       2048, 4096, 32, 2, nullptr, cx, stream);

  // ---------------- mamba block 2: DI=8192, DTR=256 ----------------
  gemm(midh, midl, 2048, m2_in_proj, 2048, xz, nullptr, nullptr,
       16384, 2048, 4, 4, nullptr, cx, stream);
  k_conv_silu<<<(128 * 8192) / 256, 256, 0, stream>>>(xz, m2_conv_w, m2_conv_b,
                                                      xc, xch, xcl, 8192);
  gemm(xch, xcl, 8192, m2_x_proj, 8192, dbc, dbch, dbcl,
       384, 8192, 128, 6, nullptr, cx, stream);
  gemm(dbch, dbcl, 384, m2_dt_w, 256, dtb, nullptr, nullptr,
       8192, 256, 8, 5, m2_dt_b, cx, stream);
  k_scan<<<2048, 256, 0, stream>>>(dtb, xc, dbc, m2_A_log, m2_D, yb, 8192, 256);
  k_gate<<<(128 * 8192) / 256, 256, 0, stream>>>(yb, xz, ybh, ybl, 8192, 13);
  gemm(ybh, ybl, 8192, m2_out_proj, 8192, (float*)d_out, nullptr, nullptr,
       4096, 8192, 16, 4, nullptr, cx, stream);
}